// Round 15
// baseline (197.343 us; speedup 1.0000x reference)
//
#include <hip/hip_runtime.h>

// TwoTwoNet: rank-2 recurrence collapse, round 14 — half-wave dual-batch.
// Two batches per wave: lanes 0-31 = batch A, 32-63 = batch B, each lane owns
// 32 channels (16 f32x2 pairs). The inner pass / h-sums / butterfly are ONE
// instruction stream serving BOTH batches -> per-batch issue halves.
// Reduce: 5-level intra-half butterfly (xor1,2 quad_perm; xor4 half_mirror;
// xor8 mirror via update_dpp builtin; xor16 via ds_swizzle 0x401F). Result is
// per-half-uniform in VGPRs: q1,q2 never touch SGPRs (no readlane, no hazard).
// x_t per-half broadcast via ds_bpermute (addr = (t | (lane&32))<<2),
// prefetched one step ahead so LDS latency hides under the inner pass.
// Math (verified R3-R13): al = q1 + x_t*A1, be = q2 + x_t*A2;
//   m = clip(al*d + be*e, -1, 1); q1' = <m,g1>, q2' = <m,g2>, out = <m,wo>;
//   g1 = w00*mask*d + w01*mask*e, g2 = w10*mask*d + w11*mask*e.

typedef float f32x2 __attribute__((ext_vector_type(2)));

constexpr int Bc = 256;
constexpr int Tc = 512;
constexpr int NCH = 16;        // 16 chunks of 32 steps

__device__ __forceinline__ f32x2 pk_fma(f32x2 a, f32x2 b, f32x2 c) {
    f32x2 d;
    asm("v_pk_fma_f32 %0, %1, %2, %3" : "=v"(d) : "v"(a), "v"(b), "v"(c));
    return d;
}
__device__ __forceinline__ f32x2 pk_mul(f32x2 a, f32x2 b) {
    f32x2 d;
    asm("v_pk_mul_f32 %0, %1, %2" : "=v"(d) : "v"(a), "v"(b));
    return d;
}

// One butterfly level via update_dpp builtin (proven-compiling path).
template <int CTRL>
__device__ __forceinline__ float bf_dpp(float v) {
    int t = __builtin_amdgcn_update_dpp(0, __float_as_int(v), CTRL, 0xf, 0xf, true);
    return v + __int_as_float(t);
}

// 5-level intra-half butterfly on 3 chains (xor1,2,4,8 DPP; xor16 swizzle).
// After this, each value is uniform within its 32-lane half (= per-batch sum).
#define BF5_3(h1, h2, h3) do {                                        \
    h1 = bf_dpp<0xB1>(h1);  h2 = bf_dpp<0xB1>(h2);  h3 = bf_dpp<0xB1>(h3); \
    h1 = bf_dpp<0x4E>(h1);  h2 = bf_dpp<0x4E>(h2);  h3 = bf_dpp<0x4E>(h3); \
    h1 = bf_dpp<0x141>(h1); h2 = bf_dpp<0x141>(h2); h3 = bf_dpp<0x141>(h3); \
    h1 = bf_dpp<0x140>(h1); h2 = bf_dpp<0x140>(h2); h3 = bf_dpp<0x140>(h3); \
    h1 += __int_as_float(__builtin_amdgcn_ds_swizzle(__float_as_int(h1), 0x401F)); \
    h2 += __int_as_float(__builtin_amdgcn_ds_swizzle(__float_as_int(h2), 0x401F)); \
    h3 += __int_as_float(__builtin_amdgcn_ds_swizzle(__float_as_int(h3), 0x401F)); \
} while (0)

#define DECL_TBL(i) f32x2 d2_##i, e2_##i, g1_##i, g2_##i, wo_##i

#define INIT_TBL(i) do { \
    _Pragma("unroll") \
    for (int h = 0; h < 2; ++h) { \
        const int c = l31 + 32 * (2 * (i) + h); \
        const float dv   = dec_orth[c]; \
        const float ev   = enc_orth[c]; \
        const float mv   = mask[c]; \
        const float encv = encoder[c]; \
        const float decv = decoder[c]; \
        const float s0v  = state0[c]; \
        const float mdv = mv * dv, mev = mv * ev; \
        d2_##i[h]  = dv;  e2_##i[h]  = ev; \
        g1_##i[h] = fmaf(w00, mdv, w01 * mev); \
        g2_##i[h] = fmaf(w10, mdv, w11 * mev); \
        wo_##i[h] = mv * decv; \
        s0d += s0v * dv;  s0e += s0v * ev; \
        kd = fmaf(mv * encv, dv, kd); \
        ke = fmaf(mv * encv, ev, ke); \
    } \
} while (0)

#define ACC_J(i) do { \
    f32x2 tt = pk_fma(b2, e2_##i, pk_mul(a2, d2_##i)); \
    f32x2 mm; \
    mm.x = __builtin_amdgcn_fmed3f(tt.x, -1.0f, 1.0f); \
    mm.y = __builtin_amdgcn_fmed3f(tt.y, -1.0f, 1.0f); \
    p1 = pk_fma(mm, g1_##i, p1); \
    p2 = pk_fma(mm, g2_##i, p2); \
    po = pk_fma(mm, wo_##i, po); \
} while (0)

#define ACC_J0(i) do { \
    f32x2 tt = pk_fma(b2, e2_##i, pk_mul(a2, d2_##i)); \
    f32x2 mm; \
    mm.x = __builtin_amdgcn_fmed3f(tt.x, -1.0f, 1.0f); \
    mm.y = __builtin_amdgcn_fmed3f(tt.y, -1.0f, 1.0f); \
    p1 = pk_mul(mm, g1_##i); \
    p2 = pk_mul(mm, g2_##i); \
    po = pk_mul(mm, wo_##i); \
} while (0)

__global__ __attribute__((amdgpu_waves_per_eu(1, 1))) __launch_bounds__(64)
void twotwonet_kernel(
    const float* __restrict__ x,        // [B, T]
    const float* __restrict__ state0,   // [n]
    const float* __restrict__ mask,     // [n]
    const float* __restrict__ w,        // [2,2]
    const float* __restrict__ dec_orth, // [n]
    const float* __restrict__ enc_orth, // [n]
    const float* __restrict__ decoder,  // [n]
    const float* __restrict__ encoder,  // [n]
    float* __restrict__ out)            // [B, T]
{
    const int b0   = 2 * blockIdx.x;        // batches b0 (lanes 0-31), b0+1 (32-63)
    const int lane = threadIdx.x;           // 0..63
    const int l31  = lane & 31;
    const int half = lane >> 5;
    const int h32x4 = (lane & 32) << 2;     // bpermute addr base for this half

    const float w00 = w[0], w01 = w[1], w10 = w[2], w11 = w[3];

    DECL_TBL(0);  DECL_TBL(1);  DECL_TBL(2);  DECL_TBL(3);
    DECL_TBL(4);  DECL_TBL(5);  DECL_TBL(6);  DECL_TBL(7);
    DECL_TBL(8);  DECL_TBL(9);  DECL_TBL(10); DECL_TBL(11);
    DECL_TBL(12); DECL_TBL(13); DECL_TBL(14); DECL_TBL(15);

    float s0d = 0.f, s0e = 0.f, kd = 0.f, ke = 0.f;
    INIT_TBL(0);  INIT_TBL(1);  INIT_TBL(2);  INIT_TBL(3);
    INIT_TBL(4);  INIT_TBL(5);  INIT_TBL(6);  INIT_TBL(7);
    INIT_TBL(8);  INIT_TBL(9);  INIT_TBL(10); INIT_TBL(11);
    INIT_TBL(12); INIT_TBL(13); INIT_TBL(14); INIT_TBL(15);

    // Intra-half init reduce (xor up to 16 stays within each 32-lane half).
#pragma unroll
    for (int m = 16; m >= 1; m >>= 1) {
        s0d += __shfl_xor(s0d, m, 64);
        s0e += __shfl_xor(s0e, m, 64);
        kd  += __shfl_xor(kd, m, 64);
        ke  += __shfl_xor(ke, m, 64);
    }

    const float A1 = fmaf(w00, kd, w01 * ke);
    const float A2 = fmaf(w10, kd, w11 * ke);

    // Per-half carried state, uniform within half, in VGPRs throughout.
    float q1 = fmaf(w00, s0d, w01 * s0e);
    float q2 = fmaf(w10, s0d, w11 * s0e);

    const float* xrow = x + (size_t)(b0 + half) * Tc;   // per-half batch row

    for (int c = 0; c < NCH; ++c) {
        // Stage this chunk's 32 x values per half, prescaled by A1/A2.
        const float xv = xrow[l31 + 32 * c];
        const float xs1v = xv * A1;
        const float xs2v = xv * A2;

        // Prologue broadcast for t2 = 0.
        float xs1 = __int_as_float(__builtin_amdgcn_ds_bpermute(h32x4, __float_as_int(xs1v)));
        float xs2 = __int_as_float(__builtin_amdgcn_ds_bpermute(h32x4, __float_as_int(xs2v)));

        float obuf = 0.f;
#pragma unroll 2
        for (int t2 = 0; t2 < 32; ++t2) {
            // Prefetch next step's broadcast (independent of q -> hides LDS lat).
            const int nt4 = (((t2 + 1) & 31) << 2) + h32x4;
            const float xs1n = __int_as_float(__builtin_amdgcn_ds_bpermute(nt4, __float_as_int(xs1v)));
            const float xs2n = __int_as_float(__builtin_amdgcn_ds_bpermute(nt4, __float_as_int(xs2v)));

            const float al = q1 + xs1;
            const float be = q2 + xs2;
            const f32x2 a2 = {al, al};
            const f32x2 b2 = {be, be};

            f32x2 p1, p2, po;
            ACC_J0(0);
            ACC_J(1);  ACC_J(2);  ACC_J(3);
            ACC_J(4);  ACC_J(5);  ACC_J(6);  ACC_J(7);
            ACC_J(8);  ACC_J(9);  ACC_J(10); ACC_J(11);
            ACC_J(12); ACC_J(13); ACC_J(14); ACC_J(15);

            float h1 = p1.x + p1.y;
            float h2 = p2.x + p2.y;
            float ho = po.x + po.y;

            BF5_3(h1, h2, ho);      // per-half totals, uniform in each half

            q1 = h1;                // stays in VGPR
            q2 = h2;

            obuf = (t2 == l31) ? ho : obuf;
            xs1 = xs1n;
            xs2 = xs2n;
        }
        out[(size_t)(b0 + half) * Tc + 32 * c + l31] = obuf;
    }
}

extern "C" void kernel_launch(void* const* d_in, const int* in_sizes, int n_in,
                              void* d_out, int out_size, void* d_ws, size_t ws_size,
                              hipStream_t stream) {
    const float* x        = (const float*)d_in[0];
    const float* state0   = (const float*)d_in[1];
    const float* mask     = (const float*)d_in[2];
    const float* w        = (const float*)d_in[3];
    const float* dec_orth = (const float*)d_in[4];
    const float* enc_orth = (const float*)d_in[5];
    const float* decoder  = (const float*)d_in[6];
    const float* encoder  = (const float*)d_in[7];
    float* out = (float*)d_out;

    twotwonet_kernel<<<dim3(Bc / 2), dim3(64), 0, stream>>>(
        x, state0, mask, w, dec_orth, enc_orth, decoder, encoder, out);
}